// Round 1
// baseline (1754.431 us; speedup 1.0000x reference)
//
#include <hip/hip_runtime.h>

// UniRNN: T=512,B=256,X=H1=H2=256, fp32 in/out.
// Split-precision (bf16 hi+lo) MFMA pipeline:
//   K1: x1 = A @ W_ih1^T + b_ih1        (A split, W split, fp32 out -> d_out)
//   K2: layer-1 scan, state split, W_hh1 split; h1 stream bf16 -> d_ws
//   K3: u  = h1 @ W_ih2^T + b_ih2+b_hh2 (A=h1 bf16, W split, fp32 -> d_out)
//   K4: layer-2 scan in place over u -> final output
// d_ws requirement: T*B*H*2 = 67,108,864 bytes.
//
// R1 changes (scan kernels only):
//  - one-step register prefetch of x1/u (hide ~900cy HBM latency)
//  - lgkmcnt-only barrier in scan loop (no vmcnt(0) drain per step)
//  - accumulators split kc 0-3 / 4-7 (12-deep dependent MFMA chains, not 24)
//  - per-kc JIT LDS fragment reads (VGPR relief for the above)

#define TT 512
#define BB 256
#define HH 256
#define LSTR 280   // LDS row stride (bf16 elems)

typedef short bf16x8 __attribute__((ext_vector_type(8)));
typedef float f32x4  __attribute__((ext_vector_type(4)));

__device__ inline unsigned short f2bf(float f) {
    unsigned int u = __float_as_uint(f);
    u = u + 0x7fffu + ((u >> 16) & 1u);          // RNE
    return (unsigned short)(u >> 16);
}
__device__ inline float bf2f(unsigned short h) {
    return __uint_as_float(((unsigned int)h) << 16);
}
__device__ inline float tanh_fast(float x) {
    float e = __expf(2.0f * x);
    return 1.0f - 2.0f * __builtin_amdgcn_rcpf(e + 1.0f);
}
// LDS-visibility-only barrier: waits DS ops, does NOT drain vmcnt.
// Global stores / prefetch loads stay in flight across it (T4 discipline).
__device__ inline void lds_barrier() {
    asm volatile("s_waitcnt lgkmcnt(0)\n\ts_barrier" ::: "memory");
}
// 8 consecutive fp32 -> hi/lo bf16x8 fragments (split precision)
__device__ inline void pack_wfrag2(const float* __restrict__ wrow, bf16x8& hi, bf16x8& lo) {
    const float4* p = (const float4*)wrow;
    float4 v0 = p[0], v1 = p[1];
    float w[8] = {v0.x, v0.y, v0.z, v0.w, v1.x, v1.y, v1.z, v1.w};
#pragma unroll
    for (int i = 0; i < 8; ++i) {
        unsigned short h = f2bf(w[i]);
        hi[i] = (short)h;
        lo[i] = (short)f2bf(w[i] - bf2f(h));
    }
}
__device__ inline f32x4 mfma16(bf16x8 a, bf16x8 b, f32x4 c) {
    return __builtin_amdgcn_mfma_f32_16x16x32_bf16(a, b, c, 0, 0, 0);
}

// ---------------------------------------------------------------------------
// Projection GEMM: C[m,n] = sum_k A[m,k]*W[n,k] + bias(n), fp32 out.
// M = T*B = 131072, N = K = 256. Block 512 thr (8 waves), wave owns 32 cols.
// Tile 64(M) x 256(N); each WG does 4 tiles -> grid 512.
// W always split (hi+lo). SPLIT_A: also split activations (fp32 input path).
// Passes: Ahi@Whi [+ Alo@Whi if SPLIT_A] + Ahi@Wlo.
// ---------------------------------------------------------------------------
template<bool IN_BF16, bool SPLIT_A>
__global__ __launch_bounds__(512, 2)
void proj_kernel(const void* __restrict__ Ain, const float* __restrict__ W,
                 const float* __restrict__ bias_a, const float* __restrict__ bias_b,
                 float* __restrict__ Cout)
{
    __shared__ unsigned short lds_hi[64 * LSTR];
    __shared__ unsigned short lds_lo[SPLIT_A ? 64 * LSTR : 1];
    const int tid  = threadIdx.x;
    const int lane = tid & 63, wv = tid >> 6;
    const int quad = lane >> 4, l15 = lane & 15;
    const int n0   = wv * 32;

    bf16x8 wh[2][8], wl[2][8];
    float  biasv[2];
#pragma unroll
    for (int nt = 0; nt < 2; ++nt) {
        int n = n0 + nt * 16 + l15;
        biasv[nt] = bias_a[n] + (bias_b ? bias_b[n] : 0.0f);
#pragma unroll
        for (int kc = 0; kc < 8; ++kc)
            pack_wfrag2(W + (size_t)n * HH + kc * 32 + quad * 8, wh[nt][kc], wl[nt][kc]);
    }

    for (int it = 0; it < 4; ++it) {
        const int m0 = (blockIdx.x * 4 + it) * 64;
        if (IN_BF16) {
            const unsigned short* A = (const unsigned short*)Ain;
#pragma unroll
            for (int j = 0; j < 4; ++j) {
                int c = tid + j * 512;            // 2048 chunks of 8 bf16
                int row = c >> 5, col8 = c & 31;
                uint4 v = *(const uint4*)(A + (size_t)(m0 + row) * HH + col8 * 8);
                *(uint4*)&lds_hi[row * LSTR + col8 * 8] = v;
            }
        } else {
            const float* A = (const float*)Ain;
#pragma unroll
            for (int j = 0; j < 8; ++j) {
                int c = tid + j * 512;            // 4096 chunks of 4 fp32
                int row = c >> 6, col4 = c & 63;
                float4 v = *(const float4*)(A + (size_t)(m0 + row) * HH + col4 * 4);
                unsigned short h0 = f2bf(v.x), h1 = f2bf(v.y), h2 = f2bf(v.z), h3 = f2bf(v.w);
                unsigned int p0 = (unsigned int)h0 | ((unsigned int)h1 << 16);
                unsigned int p1 = (unsigned int)h2 | ((unsigned int)h3 << 16);
                *(uint2*)&lds_hi[row * LSTR + col4 * 4] = make_uint2(p0, p1);
                if (SPLIT_A) {
                    unsigned int q0 = (unsigned int)f2bf(v.x - bf2f(h0)) |
                                      ((unsigned int)f2bf(v.y - bf2f(h1)) << 16);
                    unsigned int q1 = (unsigned int)f2bf(v.z - bf2f(h2)) |
                                      ((unsigned int)f2bf(v.w - bf2f(h3)) << 16);
                    *(uint2*)&lds_lo[row * LSTR + col4 * 4] = make_uint2(q0, q1);
                }
            }
        }
        __syncthreads();

        f32x4 acc[4][2];
#pragma unroll
        for (int mt = 0; mt < 4; ++mt)
#pragma unroll
            for (int nt = 0; nt < 2; ++nt)
                acc[mt][nt] = (f32x4){0.f, 0.f, 0.f, 0.f};

#pragma unroll
        for (int kc = 0; kc < 8; ++kc) {
            bf16x8 ah[4], al[4];
#pragma unroll
            for (int mt = 0; mt < 4; ++mt) {
                ah[mt] = *(const bf16x8*)&lds_hi[(mt * 16 + l15) * LSTR + kc * 32 + quad * 8];
                if (SPLIT_A)
                    al[mt] = *(const bf16x8*)&lds_lo[(mt * 16 + l15) * LSTR + kc * 32 + quad * 8];
            }
#pragma unroll
            for (int mt = 0; mt < 4; ++mt)
#pragma unroll
                for (int nt = 0; nt < 2; ++nt) {
                    acc[mt][nt] = mfma16(ah[mt], wh[nt][kc], acc[mt][nt]);
                    if (SPLIT_A)
                        acc[mt][nt] = mfma16(al[mt], wh[nt][kc], acc[mt][nt]);
                    acc[mt][nt] = mfma16(ah[mt], wl[nt][kc], acc[mt][nt]);
                }
        }

#pragma unroll
        for (int mt = 0; mt < 4; ++mt)
#pragma unroll
            for (int nt = 0; nt < 2; ++nt)
#pragma unroll
                for (int r = 0; r < 4; ++r) {
                    int row = m0 + mt * 16 + quad * 4 + r;
                    int col = n0 + nt * 16 + l15;
                    Cout[(size_t)row * HH + col] = acc[mt][nt][r] + biasv[nt];
                }
        __syncthreads();
    }
}

// ---------------------------------------------------------------------------
// Layer-1 scan: 16 WGs x 512 thr. WG owns batch rows [m0,m0+16), wave owns
// 32 cols. State split hi+lo bf16 in LDS, W_hh1 split in VGPRs.
// 3 MFMA passes/step: hi@Whi + lo@Whi + hi@Wlo.
// Per-step: prefetch x(t+1) in regs, split acc chains, lgkm-only barrier.
// ---------------------------------------------------------------------------
__global__ __launch_bounds__(512, 2)
void scan1_kernel(const float* __restrict__ x1,             // [T,B,H] fp32
                  const float* __restrict__ Whh1,
                  const float* __restrict__ bhh1,
                  const float* __restrict__ h0,             // [B,H] fp32
                  unsigned short* __restrict__ h1g,         // [T,B,H] bf16 out
                  float* __restrict__ h1f)                  // [B,H] fp32 final
{
    __shared__ unsigned short hs_hi[2][16 * LSTR];
    __shared__ unsigned short hs_lo[2][16 * LSTR];
    const int tid  = threadIdx.x;
    const int lane = tid & 63, wv = tid >> 6;
    const int quad = lane >> 4, l15 = lane & 15;
    const int m0   = blockIdx.x * 16;
    const int n0   = wv * 32;

    bf16x8 wh[2][8], wl[2][8];
    float  biasv[2];
#pragma unroll
    for (int nt = 0; nt < 2; ++nt) {
        int n = n0 + nt * 16 + l15;
        biasv[nt] = bhh1[n];
#pragma unroll
        for (int kc = 0; kc < 8; ++kc)
            pack_wfrag2(Whh1 + (size_t)n * HH + kc * 32 + quad * 8, wh[nt][kc], wl[nt][kc]);
    }
#pragma unroll
    for (int j = 0; j < 8; ++j) {
        int idx = tid + j * 512;
        int row = idx >> 8, col = idx & 255;
        float v = h0[(size_t)(m0 + row) * HH + col];
        unsigned short h = f2bf(v);
        hs_hi[0][row * LSTR + col] = h;
        hs_lo[0][row * LSTR + col] = f2bf(v - bf2f(h));
    }
    __syncthreads();

    const int colb = n0 + l15;
    const int rowb = quad * 4;

    // prefetch x(t=0)
    float xc[2][4];
#pragma unroll
    for (int nt = 0; nt < 2; ++nt)
#pragma unroll
        for (int r = 0; r < 4; ++r)
            xc[nt][r] = x1[(size_t)(m0 + rowb + r) * HH + colb + nt * 16];

    for (int t = 0; t < TT; ++t) {
        const int cur = t & 1, nxt = (t + 1) & 1;
        const size_t base = ((size_t)t * BB + m0) * HH;
        const int tn = (t + 1 < TT) ? (t + 1) : t;          // clamp (values unused on last iter)
        const size_t basen = ((size_t)tn * BB + m0) * HH;

        // prefetch x(t+1): consumed one full step later
        float xn[2][4];
#pragma unroll
        for (int nt = 0; nt < 2; ++nt)
#pragma unroll
            for (int r = 0; r < 4; ++r)
                xn[nt][r] = x1[basen + (size_t)(rowb + r) * HH + colb + nt * 16];

        f32x4 accA[2] = {(f32x4){0.f,0.f,0.f,0.f}, (f32x4){0.f,0.f,0.f,0.f}};
        f32x4 accB[2] = {(f32x4){0.f,0.f,0.f,0.f}, (f32x4){0.f,0.f,0.f,0.f}};
#pragma unroll
        for (int kc = 0; kc < 4; ++kc) {
            const int kd = kc + 4;
            bf16x8 ahA = *(const bf16x8*)&hs_hi[cur][l15 * LSTR + kc * 32 + quad * 8];
            bf16x8 alA = *(const bf16x8*)&hs_lo[cur][l15 * LSTR + kc * 32 + quad * 8];
            bf16x8 ahB = *(const bf16x8*)&hs_hi[cur][l15 * LSTR + kd * 32 + quad * 8];
            bf16x8 alB = *(const bf16x8*)&hs_lo[cur][l15 * LSTR + kd * 32 + quad * 8];
#pragma unroll
            for (int nt = 0; nt < 2; ++nt) {
                accA[nt] = mfma16(ahA, wh[nt][kc], accA[nt]);
                accA[nt] = mfma16(alA, wh[nt][kc], accA[nt]);
                accA[nt] = mfma16(ahA, wl[nt][kc], accA[nt]);
                accB[nt] = mfma16(ahB, wh[nt][kd], accB[nt]);
                accB[nt] = mfma16(alB, wh[nt][kd], accB[nt]);
                accB[nt] = mfma16(ahB, wl[nt][kd], accB[nt]);
            }
        }

#pragma unroll
        for (int nt = 0; nt < 2; ++nt) {
            f32x4 acc = accA[nt] + accB[nt];
#pragma unroll
            for (int r = 0; r < 4; ++r) {
                float pre = acc[r] + xc[nt][r] + biasv[nt];
                float h   = tanh_fast(pre);
                unsigned short hb = f2bf(h);
                int row = rowb + r, col = colb + nt * 16;
                hs_hi[nxt][row * LSTR + col] = hb;
                hs_lo[nxt][row * LSTR + col] = f2bf(h - bf2f(hb));
                h1g[base + (size_t)row * HH + col] = hb;
                if (t == TT - 1) h1f[(size_t)(m0 + row) * HH + col] = h;
            }
        }
        lds_barrier();
#pragma unroll
        for (int nt = 0; nt < 2; ++nt)
#pragma unroll
            for (int r = 0; r < 4; ++r)
                xc[nt][r] = xn[nt][r];
    }
}

// ---------------------------------------------------------------------------
// Layer-2 scan: same structure; u fp32 in/out in place (biases pre-folded).
// ---------------------------------------------------------------------------
__global__ __launch_bounds__(512, 2)
void scan2_kernel(float* __restrict__ u,                    // [T,B,H] fp32, in/out
                  const float* __restrict__ Whh2,
                  const float* __restrict__ h0,             // [B,H] fp32
                  float* __restrict__ h2f)                  // [B,H] fp32 final
{
    __shared__ unsigned short hs_hi[2][16 * LSTR];
    __shared__ unsigned short hs_lo[2][16 * LSTR];
    const int tid  = threadIdx.x;
    const int lane = tid & 63, wv = tid >> 6;
    const int quad = lane >> 4, l15 = lane & 15;
    const int m0   = blockIdx.x * 16;
    const int n0   = wv * 32;

    bf16x8 wh[2][8], wl[2][8];
#pragma unroll
    for (int nt = 0; nt < 2; ++nt) {
        int n = n0 + nt * 16 + l15;
#pragma unroll
        for (int kc = 0; kc < 8; ++kc)
            pack_wfrag2(Whh2 + (size_t)n * HH + kc * 32 + quad * 8, wh[nt][kc], wl[nt][kc]);
    }
#pragma unroll
    for (int j = 0; j < 8; ++j) {
        int idx = tid + j * 512;
        int row = idx >> 8, col = idx & 255;
        float v = h0[(size_t)(m0 + row) * HH + col];
        unsigned short h = f2bf(v);
        hs_hi[0][row * LSTR + col] = h;
        hs_lo[0][row * LSTR + col] = f2bf(v - bf2f(h));
    }
    __syncthreads();

    const int colb = n0 + l15;
    const int rowb = quad * 4;

    // prefetch u(t=0)
    float uc[2][4];
#pragma unroll
    for (int nt = 0; nt < 2; ++nt)
#pragma unroll
        for (int r = 0; r < 4; ++r)
            uc[nt][r] = u[(size_t)(m0 + rowb + r) * HH + colb + nt * 16];

    for (int t = 0; t < TT; ++t) {
        const int cur = t & 1, nxt = (t + 1) & 1;
        const size_t base = ((size_t)t * BB + m0) * HH;
        const int tn = (t + 1 < TT) ? (t + 1) : t;
        const size_t basen = ((size_t)tn * BB + m0) * HH;

        // prefetch u(t+1); on last iter reads u(t) BEFORE this step's in-place
        // write (program order per lane) -> stale values, discarded. Safe.
        float un[2][4];
#pragma unroll
        for (int nt = 0; nt < 2; ++nt)
#pragma unroll
            for (int r = 0; r < 4; ++r)
                un[nt][r] = u[basen + (size_t)(rowb + r) * HH + colb + nt * 16];

        f32x4 accA[2] = {(f32x4){0.f,0.f,0.f,0.f}, (f32x4){0.f,0.f,0.f,0.f}};
        f32x4 accB[2] = {(f32x4){0.f,0.f,0.f,0.f}, (f32x4){0.f,0.f,0.f,0.f}};
#pragma unroll
        for (int kc = 0; kc < 4; ++kc) {
            const int kd = kc + 4;
            bf16x8 ahA = *(const bf16x8*)&hs_hi[cur][l15 * LSTR + kc * 32 + quad * 8];
            bf16x8 alA = *(const bf16x8*)&hs_lo[cur][l15 * LSTR + kc * 32 + quad * 8];
            bf16x8 ahB = *(const bf16x8*)&hs_hi[cur][l15 * LSTR + kd * 32 + quad * 8];
            bf16x8 alB = *(const bf16x8*)&hs_lo[cur][l15 * LSTR + kd * 32 + quad * 8];
#pragma unroll
            for (int nt = 0; nt < 2; ++nt) {
                accA[nt] = mfma16(ahA, wh[nt][kc], accA[nt]);
                accA[nt] = mfma16(alA, wh[nt][kc], accA[nt]);
                accA[nt] = mfma16(ahA, wl[nt][kc], accA[nt]);
                accB[nt] = mfma16(ahB, wh[nt][kd], accB[nt]);
                accB[nt] = mfma16(alB, wh[nt][kd], accB[nt]);
                accB[nt] = mfma16(ahB, wl[nt][kd], accB[nt]);
            }
        }

#pragma unroll
        for (int nt = 0; nt < 2; ++nt) {
            f32x4 acc = accA[nt] + accB[nt];
#pragma unroll
            for (int r = 0; r < 4; ++r) {
                float pre = acc[r] + uc[nt][r];
                float h   = tanh_fast(pre);
                unsigned short hb = f2bf(h);
                int row = rowb + r, col = colb + nt * 16;
                hs_hi[nxt][row * LSTR + col] = hb;
                hs_lo[nxt][row * LSTR + col] = f2bf(h - bf2f(hb));
                u[base + (size_t)row * HH + col] = h;       // final output
                if (t == TT - 1) h2f[(size_t)(m0 + row) * HH + col] = h;
            }
        }
        lds_barrier();
#pragma unroll
        for (int nt = 0; nt < 2; ++nt)
#pragma unroll
            for (int r = 0; r < 4; ++r)
                uc[nt][r] = un[nt][r];
    }
}

extern "C" void kernel_launch(void* const* d_in, const int* in_sizes, int n_in,
                              void* d_out, int out_size, void* d_ws, size_t ws_size,
                              hipStream_t stream)
{
    const float* A     = (const float*)d_in[0];   // [T,B,X]
    const float* is1   = (const float*)d_in[1];   // [B,H1]
    const float* is2   = (const float*)d_in[2];   // [B,H2]
    const float* W_ih1 = (const float*)d_in[3];
    const float* W_hh1 = (const float*)d_in[4];
    const float* b_ih1 = (const float*)d_in[5];
    const float* b_hh1 = (const float*)d_in[6];
    const float* W_ih2 = (const float*)d_in[7];
    const float* W_hh2 = (const float*)d_in[8];
    const float* b_ih2 = (const float*)d_in[9];
    const float* b_hh2 = (const float*)d_in[10];

    float* out = (float*)d_out;
    const size_t OUT0 = (size_t)TT * BB * HH;          // 33554432
    float* x1  = out;                                  // fp32 scratch in out region
    unsigned short* h1g = (unsigned short*)d_ws;       // bf16 h1 stream, 67 MB
    float* h1f = out + OUT0;
    float* h2f = out + OUT0 + (size_t)BB * HH;

    // K1: x1 = A @ W_ih1^T + b_ih1  (fp32, split A + split W)
    proj_kernel<false, true><<<dim3(512), dim3(512), 0, stream>>>(
        (const void*)A, W_ih1, b_ih1, nullptr, x1);
    // K2: layer-1 scan
    scan1_kernel<<<dim3(16), dim3(512), 0, stream>>>(x1, W_hh1, b_hh1, is1, h1g, h1f);
    // K3: u = h1 @ W_ih2^T + (b_ih2 + b_hh2)  (fp32 over d_out region)
    proj_kernel<true, false><<<dim3(512), dim3(512), 0, stream>>>(
        (const void*)h1g, W_ih2, b_ih2, b_hh2, out);
    // K4: layer-2 scan, in place over u -> final outputs
    scan2_kernel<<<dim3(16), dim3(512), 0, stream>>>(out, W_hh2, is2, h2f);
}